// Round 1
// baseline (3247.466 us; speedup 1.0000x reference)
//
#include <hip/hip_runtime.h>
#include <cstddef>

// ---------------------------------------------------------------------------
// Compile-time generation of real-basis Clebsch-Gordan tensors (e3nn conv.)
// ---------------------------------------------------------------------------
namespace so3 {

constexpr int IRR  = 16;    // (L_MAX+1)^2
constexpr int CIN  = 128;
constexpr int COUT = 128;
constexpr int NP   = 34;
constexpr int NNODES = 16384;
constexpr int MT   = 16;    // nodes per block

// Path enumeration: for lo in 0..3: for l1 in 0..3: for l2 in 0..3 if |l1-l2|<=lo<=l1+l2
constexpr int H_L1[NP] = {0,1,2,3, 0,1,1,1,2,2,2,3,3, 0,1,1,1,2,2,2,2,3,3,3, 0,1,1,2,2,2,3,3,3,3};
constexpr int H_L2[NP] = {0,1,2,3, 1,0,1,2,1,2,3,2,3, 2,1,2,3,0,1,2,3,1,2,3, 3,2,3,1,2,3,0,1,2,3};
constexpr int H_LO[NP] = {0,0,0,0, 1,1,1,1,1,1,1,1,1, 2,2,2,2,2,2,2,2,2,2,2, 3,3,3,3,3,3,3,3,3,3};
constexpr int H_START[4] = {0,4,13,24};
constexpr int H_CNT[4]   = {4,9,11,10};

constexpr double cfac(int n){ double r=1.0; for(int i=2;i<=n;++i) r *= (double)i; return r; }
constexpr double csqrt_(double x){
  if(x <= 0.0) return 0.0;
  double r = x < 1.0 ? 1.0 : x;
  for(int i=0;i<60;++i) r = 0.5*(r + x/r);
  return r;
}
constexpr double m1pow(int k){ return (k & 1) ? -1.0 : 1.0; }

struct CD { double re, im; };
constexpr CD cmul(CD a, CD b){ return CD{a.re*b.re - a.im*b.im, a.re*b.im + a.im*b.re}; }

struct CGDense { double v[7][7][7]; };   // [m1+j1][m2+j2][m3+j3]
constexpr CGDense su2_cg(int j1,int j2,int j3){
  CGDense C{};
  for(int m1=-j1;m1<=j1;++m1){
    for(int m2=-j2;m2<=j2;++m2){
      int m3 = m1+m2;
      if(m3 < -j3 || m3 > j3) continue;
      double pref = csqrt_((2*j3+1) * cfac(j3+j1-j2)*cfac(j3-j1+j2)*cfac(j1+j2-j3)/cfac(j1+j2+j3+1));
      pref *= csqrt_(cfac(j3+m3)*cfac(j3-m3)*cfac(j1-m1)*cfac(j1+m1)*cfac(j2-m2)*cfac(j2+m2));
      double s = 0.0;
      for(int k=0;k<=j1+j2;++k){
        int d0=k, d1=j1+j2-j3-k, d2=j1-m1-k, d3=j2+m2-k, d4=j3-j2+m1+k, d5=j3-j1-m2+k;
        if(d0<0||d1<0||d2<0||d3<0||d4<0||d5<0) continue;
        s += m1pow(k)/(cfac(d0)*cfac(d1)*cfac(d2)*cfac(d3)*cfac(d4)*cfac(d5));
      }
      C.v[m1+j1][m2+j2][m3+j3] = pref*s;
    }
  }
  return C;
}

struct QMat { CD v[7][7]; };             // real->complex change of basis
constexpr QMat qmat(int l){
  QMat q{};
  const double r2 = 1.0/csqrt_(2.0);
  for(int m=-l;m<0;++m){
    q.v[l+m][l-m] = CD{r2, 0.0};         // col l+|m|
    q.v[l+m][l+m] = CD{0.0, -r2};        // col l-|m|
  }
  q.v[l][l] = CD{1.0, 0.0};
  for(int m=1;m<=l;++m){
    double sgn = m1pow(m);
    q.v[l+m][l+m] = CD{sgn*r2, 0.0};
    q.v[l+m][l-m] = CD{0.0, sgn*r2};
  }
  CD ph = CD{1.0, 0.0};                  // (-i)^l
  int lm = l & 3;
  if(lm==1) ph = CD{0.0,-1.0};
  else if(lm==2) ph = CD{-1.0,0.0};
  else if(lm==3) ph = CD{0.0, 1.0};
  for(int i=0;i<2*l+1;++i)
    for(int j=0;j<2*l+1;++j)
      q.v[i][j] = cmul(q.v[i][j], ph);
  return q;
}

struct RealCG { double v[7][7][7]; };    // [i(a of l1)][j(b of l2)][k(c of lo)]
constexpr RealCG real_cg(int l1,int l2,int l3){
  RealCG W{};
  const CGDense C = su2_cg(l1,l2,l3);
  const QMat q1 = qmat(l1), q2 = qmat(l2), q3 = qmat(l3);
  for(int i=0;i<2*l1+1;++i){
    int alist[2] = {i, 2*l1-i};
    int na = (alist[1]==alist[0]) ? 1 : 2;   // q columns have <=2 nonzero rows
    for(int j=0;j<2*l2+1;++j){
      int blist[2] = {j, 2*l2-j};
      int nb = (blist[1]==blist[0]) ? 1 : 2;
      for(int k=0;k<2*l3+1;++k){
        int clist[2] = {k, 2*l3-k};
        int nc = (clist[1]==clist[0]) ? 1 : 2;
        double re = 0.0;
        for(int ai=0;ai<na;++ai) for(int bi=0;bi<nb;++bi) for(int ci=0;ci<nc;++ci){
          int a=alist[ai], b=blist[bi], c=clist[ci];
          double cc = C.v[a][b][c];
          if(cc == 0.0) continue;
          CD t = cmul(cmul(q1.v[a][i], q2.v[b][j]), q3.v[c][k]);
          re += t.re * cc;
        }
        W.v[i][j][k] = re;
      }
    }
  }
  return W;
}

// One constexpr variable per path keeps each constant-evaluation small.
#define DECL_CG(n,a,b,c) constexpr RealCG CGP##n = real_cg(a,b,c);
DECL_CG(0,0,0,0)  DECL_CG(1,1,1,0)  DECL_CG(2,2,2,0)  DECL_CG(3,3,3,0)
DECL_CG(4,0,1,1)  DECL_CG(5,1,0,1)  DECL_CG(6,1,1,1)  DECL_CG(7,1,2,1)
DECL_CG(8,2,1,1)  DECL_CG(9,2,2,1)  DECL_CG(10,2,3,1) DECL_CG(11,3,2,1)
DECL_CG(12,3,3,1) DECL_CG(13,0,2,2) DECL_CG(14,1,1,2) DECL_CG(15,1,2,2)
DECL_CG(16,1,3,2) DECL_CG(17,2,0,2) DECL_CG(18,2,1,2) DECL_CG(19,2,2,2)
DECL_CG(20,2,3,2) DECL_CG(21,3,1,2) DECL_CG(22,3,2,2) DECL_CG(23,3,3,2)
DECL_CG(24,0,3,3) DECL_CG(25,1,2,3) DECL_CG(26,1,3,3) DECL_CG(27,2,1,3)
DECL_CG(28,2,2,3) DECL_CG(29,2,3,3) DECL_CG(30,3,0,3) DECL_CG(31,3,1,3)
DECL_CG(32,3,2,3) DECL_CG(33,3,3,3)
#undef DECL_CG

struct CGTable { float v[NP][7][7][7]; };
constexpr CGTable pack_cg(){
  const RealCG arr[NP] = {CGP0,CGP1,CGP2,CGP3,CGP4,CGP5,CGP6,CGP7,CGP8,CGP9,
                          CGP10,CGP11,CGP12,CGP13,CGP14,CGP15,CGP16,CGP17,CGP18,CGP19,
                          CGP20,CGP21,CGP22,CGP23,CGP24,CGP25,CGP26,CGP27,CGP28,CGP29,
                          CGP30,CGP31,CGP32,CGP33};
  CGTable t{};
  for(int p=0;p<NP;++p)
    for(int i=0;i<7;++i) for(int j=0;j<7;++j) for(int k=0;k<7;++k)
      t.v[p][i][j][k] = (float)arr[p].v[i][j][k];
  return t;
}

struct Meta { int l1[NP]; int l2[NP]; float scale[NP]; };
constexpr Meta mk_meta(){
  Meta m{};
  for(int p=0;p<NP;++p){
    m.l1[p] = H_L1[p];
    m.l2[p] = H_L2[p];
    m.scale[p] = (float)(1.0/csqrt_((double)H_CNT[H_LO[p]]));
  }
  return m;
}

} // namespace so3

__constant__ so3::CGTable c_cg   = so3::pack_cg();
__constant__ so3::Meta    c_meta = so3::mk_meta();

// ---------------------------------------------------------------------------
// Kernel: one block = 16 nodes x one lo-group. FP32 VALU baseline.
// ---------------------------------------------------------------------------
template<int LO>
__launch_bounds__(256, 2)
__global__ void so3_lin_kernel(const float* __restrict__ x1,
                               const float* __restrict__ x2,
                               const float* __restrict__ w,
                               float* __restrict__ out){
  using namespace so3;
  constexpr int NR    = 2*LO + 1;
  constexpr int NPAIR = MT * NR;        // (node, c) pairs handled by this block
  constexpr int QN    = NPAIR / 2;      // accumulators per thread (2 halves of 128 v-lanes)

  __shared__ float x2s[MT * IRR];
  __shared__ float gsh[NPAIR * 8];      // g[pair][a], a-stride 8
  __shared__ alignas(16) float Tsh[NPAIR * CIN];

  const int tid  = threadIdx.x;
  const int n0   = blockIdx.x * MT;
  const int v    = tid & 127;
  const int half = tid >> 7;

  // stage x2 tile (16 nodes x 16 irreps = 256 values)
  {
    int n = tid >> 4, i = tid & 15;
    x2s[tid] = x2[(size_t)(n0 + n) * IRR + i];
  }
  __syncthreads();

  float acc[QN];
  #pragma unroll
  for(int q=0;q<QN;++q) acc[q] = 0.f;

  constexpr int PCNT = H_CNT[LO];
  for(int pp=0; pp<PCNT; ++pp){
    const int p  = H_START[LO] + pp;
    const int l1 = c_meta.l1[p];
    const int l2 = c_meta.l2[p];
    const int n1 = 2*l1 + 1;
    const int n2 = 2*l2 + 1;
    const float sc = c_meta.scale[p];

    // stage A: g[pair][a] = scale * sum_b CG[a][b][c] * x2[n, l2^2 + b]
    for(int e=tid; e < NPAIR*n1; e += 256){
      int a  = e % n1;
      int pi = e / n1;
      int c  = pi % NR;
      int n  = pi / NR;
      float s = 0.f;
      for(int b=0;b<n2;++b)
        s += c_cg.v[p][a][b][c] * x2s[n*IRR + l2*l2 + b];
      gsh[pi*8 + a] = s * sc;
    }
    __syncthreads();

    // stage B: T[pair][u] = sum_a g[pair][a] * x1[n, l1^2 + a, u]
    for(int e=tid; e < NPAIR*CIN; e += 256){
      int u  = e & 127;
      int pi = e >> 7;
      int n  = pi / NR;
      const float* x1p = x1 + ((size_t)(n0 + n) * IRR + l1*l1) * CIN + u;
      float s = 0.f;
      for(int a=0;a<n1;++a)
        s += gsh[pi*8 + a] * x1p[a*CIN];
      Tsh[pi*CIN + u] = s;
    }
    __syncthreads();

    // stage C: acc[pair] += sum_u T[pair][u] * w[p][u][v]
    const float* wp = w + (size_t)p * CIN * COUT;
    for(int u0=0; u0<CIN; u0+=8){
      float w8[8];
      #pragma unroll
      for(int j=0;j<8;++j) w8[j] = wp[(u0+j)*COUT + v];
      #pragma unroll
      for(int q=0;q<QN;++q){
        int pi = 2*q + half;
        const float4* tp = reinterpret_cast<const float4*>(&Tsh[pi*CIN + u0]);
        float4 t0 = tp[0], t1 = tp[1];   // wave-uniform address -> LDS broadcast
        acc[q] += t0.x*w8[0] + t0.y*w8[1] + t0.z*w8[2] + t0.w*w8[3]
                + t1.x*w8[4] + t1.y*w8[5] + t1.z*w8[6] + t1.w*w8[7];
      }
    }
    __syncthreads();
  }

  // write out: rows lo^2 .. lo^2+2lo of each node, written exactly once
  #pragma unroll
  for(int q=0;q<QN;++q){
    int pi = 2*q + half;
    int c  = pi % NR;
    int n  = pi / NR;
    out[((size_t)(n0 + n) * IRR + LO*LO + c) * COUT + v] = acc[q];
  }
}

extern "C" void kernel_launch(void* const* d_in, const int* in_sizes, int n_in,
                              void* d_out, int out_size, void* d_ws, size_t ws_size,
                              hipStream_t stream){
  (void)in_sizes; (void)n_in; (void)d_ws; (void)ws_size; (void)out_size;
  const float* x1 = (const float*)d_in[0];   // (16384, 16, 128) f32
  const float* x2 = (const float*)d_in[1];   // (16384, 16)      f32
  const float* w  = (const float*)d_in[2];   // (34, 128, 128)   f32
  float* out = (float*)d_out;                // (16384, 16, 128) f32

  dim3 grid(so3::NNODES / so3::MT);
  dim3 block(256);
  so3_lin_kernel<0><<<grid, block, 0, stream>>>(x1, x2, w, out);
  so3_lin_kernel<1><<<grid, block, 0, stream>>>(x1, x2, w, out);
  so3_lin_kernel<2><<<grid, block, 0, stream>>>(x1, x2, w, out);
  so3_lin_kernel<3><<<grid, block, 0, stream>>>(x1, x2, w, out);
}

// Round 2
// 518.094 us; speedup vs baseline: 6.2681x; 6.2681x over previous
//
#include <hip/hip_runtime.h>
#include <cstddef>

// ---------------------------------------------------------------------------
// Compile-time generation of real-basis Clebsch-Gordan tensors (e3nn conv.)
// (verified correct in round 1: absmax 1.56e-2 on full f32 path)
// ---------------------------------------------------------------------------
namespace so3 {

constexpr int IRR  = 16;    // (L_MAX+1)^2
constexpr int CIN  = 128;
constexpr int COUT = 128;
constexpr int NP   = 34;
constexpr int NNODES = 16384;
constexpr int MT   = 16;    // nodes per block

constexpr int H_L1[NP] = {0,1,2,3, 0,1,1,1,2,2,2,3,3, 0,1,1,1,2,2,2,2,3,3,3, 0,1,1,2,2,2,3,3,3,3};
constexpr int H_L2[NP] = {0,1,2,3, 1,0,1,2,1,2,3,2,3, 2,1,2,3,0,1,2,3,1,2,3, 3,2,3,1,2,3,0,1,2,3};
constexpr int H_START[4] = {0,4,13,24};
constexpr int H_CNT[4]   = {4,9,11,10};

constexpr double cfac(int n){ double r=1.0; for(int i=2;i<=n;++i) r *= (double)i; return r; }
constexpr double csqrt_(double x){
  if(x <= 0.0) return 0.0;
  double r = x < 1.0 ? 1.0 : x;
  for(int i=0;i<60;++i) r = 0.5*(r + x/r);
  return r;
}
constexpr double m1pow(int k){ return (k & 1) ? -1.0 : 1.0; }

struct CD { double re, im; };
constexpr CD cmul(CD a, CD b){ return CD{a.re*b.re - a.im*b.im, a.re*b.im + a.im*b.re}; }

struct CGDense { double v[7][7][7]; };
constexpr CGDense su2_cg(int j1,int j2,int j3){
  CGDense C{};
  for(int m1=-j1;m1<=j1;++m1){
    for(int m2=-j2;m2<=j2;++m2){
      int m3 = m1+m2;
      if(m3 < -j3 || m3 > j3) continue;
      double pref = csqrt_((2*j3+1) * cfac(j3+j1-j2)*cfac(j3-j1+j2)*cfac(j1+j2-j3)/cfac(j1+j2+j3+1));
      pref *= csqrt_(cfac(j3+m3)*cfac(j3-m3)*cfac(j1-m1)*cfac(j1+m1)*cfac(j2-m2)*cfac(j2+m2));
      double s = 0.0;
      for(int k=0;k<=j1+j2;++k){
        int d0=k, d1=j1+j2-j3-k, d2=j1-m1-k, d3=j2+m2-k, d4=j3-j2+m1+k, d5=j3-j1-m2+k;
        if(d0<0||d1<0||d2<0||d3<0||d4<0||d5<0) continue;
        s += m1pow(k)/(cfac(d0)*cfac(d1)*cfac(d2)*cfac(d3)*cfac(d4)*cfac(d5));
      }
      C.v[m1+j1][m2+j2][m3+j3] = pref*s;
    }
  }
  return C;
}

struct QMat { CD v[7][7]; };
constexpr QMat qmat(int l){
  QMat q{};
  const double r2 = 1.0/csqrt_(2.0);
  for(int m=-l;m<0;++m){
    q.v[l+m][l-m] = CD{r2, 0.0};
    q.v[l+m][l+m] = CD{0.0, -r2};
  }
  q.v[l][l] = CD{1.0, 0.0};
  for(int m=1;m<=l;++m){
    double sgn = m1pow(m);
    q.v[l+m][l+m] = CD{sgn*r2, 0.0};
    q.v[l+m][l-m] = CD{0.0, sgn*r2};
  }
  CD ph = CD{1.0, 0.0};
  int lm = l & 3;
  if(lm==1) ph = CD{0.0,-1.0};
  else if(lm==2) ph = CD{-1.0,0.0};
  else if(lm==3) ph = CD{0.0, 1.0};
  for(int i=0;i<2*l+1;++i)
    for(int j=0;j<2*l+1;++j)
      q.v[i][j] = cmul(q.v[i][j], ph);
  return q;
}

struct RealCG { double v[7][7][7]; };
constexpr RealCG real_cg(int l1,int l2,int l3){
  RealCG W{};
  const CGDense C = su2_cg(l1,l2,l3);
  const QMat q1 = qmat(l1), q2 = qmat(l2), q3 = qmat(l3);
  for(int i=0;i<2*l1+1;++i){
    int alist[2] = {i, 2*l1-i};
    int na = (alist[1]==alist[0]) ? 1 : 2;
    for(int j=0;j<2*l2+1;++j){
      int blist[2] = {j, 2*l2-j};
      int nb = (blist[1]==blist[0]) ? 1 : 2;
      for(int k=0;k<2*l3+1;++k){
        int clist[2] = {k, 2*l3-k};
        int nc = (clist[1]==clist[0]) ? 1 : 2;
        double re = 0.0;
        for(int ai=0;ai<na;++ai) for(int bi=0;bi<nb;++bi) for(int ci=0;ci<nc;++ci){
          int a=alist[ai], b=blist[bi], c=clist[ci];
          double cc = C.v[a][b][c];
          if(cc == 0.0) continue;
          CD t = cmul(cmul(q1.v[a][i], q2.v[b][j]), q3.v[c][k]);
          re += t.re * cc;
        }
        W.v[i][j][k] = re;
      }
    }
  }
  return W;
}

#define DECL_CG(n,a,b,c) constexpr RealCG CGP##n = real_cg(a,b,c);
DECL_CG(0,0,0,0)  DECL_CG(1,1,1,0)  DECL_CG(2,2,2,0)  DECL_CG(3,3,3,0)
DECL_CG(4,0,1,1)  DECL_CG(5,1,0,1)  DECL_CG(6,1,1,1)  DECL_CG(7,1,2,1)
DECL_CG(8,2,1,1)  DECL_CG(9,2,2,1)  DECL_CG(10,2,3,1) DECL_CG(11,3,2,1)
DECL_CG(12,3,3,1) DECL_CG(13,0,2,2) DECL_CG(14,1,1,2) DECL_CG(15,1,2,2)
DECL_CG(16,1,3,2) DECL_CG(17,2,0,2) DECL_CG(18,2,1,2) DECL_CG(19,2,2,2)
DECL_CG(20,2,3,2) DECL_CG(21,3,1,2) DECL_CG(22,3,2,2) DECL_CG(23,3,3,2)
DECL_CG(24,0,3,3) DECL_CG(25,1,2,3) DECL_CG(26,1,3,3) DECL_CG(27,2,1,3)
DECL_CG(28,2,2,3) DECL_CG(29,2,3,3) DECL_CG(30,3,0,3) DECL_CG(31,3,1,3)
DECL_CG(32,3,2,3) DECL_CG(33,3,3,3)
#undef DECL_CG

struct CGTable { float v[NP][7][7][7]; };
constexpr CGTable pack_cg(){
  const RealCG arr[NP] = {CGP0,CGP1,CGP2,CGP3,CGP4,CGP5,CGP6,CGP7,CGP8,CGP9,
                          CGP10,CGP11,CGP12,CGP13,CGP14,CGP15,CGP16,CGP17,CGP18,CGP19,
                          CGP20,CGP21,CGP22,CGP23,CGP24,CGP25,CGP26,CGP27,CGP28,CGP29,
                          CGP30,CGP31,CGP32,CGP33};
  CGTable t{};
  for(int p=0;p<NP;++p)
    for(int i=0;i<7;++i) for(int j=0;j<7;++j) for(int k=0;k<7;++k)
      t.v[p][i][j][k] = (float)arr[p].v[i][j][k];
  return t;
}

constexpr float PATH_SC[4] = {
  (float)(1.0/csqrt_((double)H_CNT[0])), (float)(1.0/csqrt_((double)H_CNT[1])),
  (float)(1.0/csqrt_((double)H_CNT[2])), (float)(1.0/csqrt_((double)H_CNT[3]))
};

} // namespace so3

__constant__ so3::CGTable c_cg = so3::pack_cg();

typedef __attribute__((ext_vector_type(8))) short bhalf8;   // 8 bf16 (4 VGPR)
typedef __attribute__((ext_vector_type(4))) float floatx4;  // MFMA C/D

__device__ __forceinline__ unsigned f2bf(float f){           // f32 -> bf16 (RNE), low 16 bits
  unsigned u = __builtin_bit_cast(unsigned, f);
  return (u + 0x7fffu + ((u>>16)&1u)) >> 16;
}
__device__ __forceinline__ float bflo(unsigned u){ return __builtin_bit_cast(float, u<<16); }
__device__ __forceinline__ float bfhi(unsigned u){ return __builtin_bit_cast(float, u & 0xffff0000u); }

// ---------------------------------------------------------------------------
// Per-path pipelined iterator. PP in [0, CNT]; iteration PP does:
//   issue B-frag global loads for path PP   (latency hidden under A/B/barriers)
//   MFMA for path PP-1                      (reads Tsh of previous iteration)
//   stage A for path PP (g into gsh)        (overlaps MFMA in other waves' time)
//   barrier; stage B for path PP (T into Tsh, swizzled); barrier
// All indices compile-time (template recursion) -> no scratch, static acc idx.
// ---------------------------------------------------------------------------
template<int LO, int PP>
__device__ __forceinline__ void path_iter(const int tid,
    const unsigned short* __restrict__ x1s, unsigned short* __restrict__ Tsh,
    float* __restrict__ gsh, const float* __restrict__ x2s,
    const unsigned short* __restrict__ wT,
    floatx4 (&acc)[16], bhalf8 (&bfrag)[2][4])
{
  using namespace so3;
  constexpr int NR  = 2*LO + 1;
  constexpr int CNT = H_CNT[LO];
  if constexpr (PP > CNT) { return; }
  else {
    const int lane = tid & 63;
    const int wv   = tid >> 6;     // wave id = output col slice (16 cols each)
    const int lr   = lane & 15;
    const int lg   = lane >> 4;

    if constexpr (PP < CNT) {      // prefetch B-frags for path PP (global, L2-hot)
      constexpr int p = H_START[LO] + PP;
      const unsigned short* wp = wT + p*16384 + (wv*16 + lr)*128 + lg*8;
      #pragma unroll
      for (int ks = 0; ks < 4; ++ks)
        bfrag[PP & 1][ks] = *(const bhalf8*)(wp + ks*32);
    }

    if constexpr (PP > 0) {        // MFMA for path PP-1: acc += T * W
      const unsigned xr = (unsigned)((lr & 7) << 4);
      #pragma unroll
      for (int c = 0; c < NR; ++c) {
        #pragma unroll
        for (int ks = 0; ks < 4; ++ks) {
          const unsigned byte = ((unsigned)((c*16 + lr)*256) + (unsigned)(ks*64 + lg*16)) ^ xr;
          bhalf8 av = *(const bhalf8*)((const char*)Tsh + byte);
          acc[LO*LO + c] = __builtin_amdgcn_mfma_f32_16x16x32_bf16(
              av, bfrag[(PP-1) & 1][ks], acc[LO*LO + c], 0, 0, 0);
        }
      }
    }

    if constexpr (PP < CNT) {      // stage A: g[c][n][a] = sc * sum_b CG*x2
      constexpr int p  = H_START[LO] + PP;
      constexpr int l1 = H_L1[p], l2 = H_L2[p];
      constexpr int n1 = 2*l1 + 1, n2 = 2*l2 + 1;
      constexpr int GT = NR*16*8;
      #pragma unroll
      for (int e0 = 0; e0 < GT; e0 += 512) {
        const int e = e0 + tid;
        if (e < GT) {
          const int a = e & 7, n = (e >> 3) & 15, c = e >> 7;
          if (a < n1) {
            float s = 0.f;
            #pragma unroll
            for (int b = 0; b < n2; ++b)
              s += c_cg.v[p][a][b][c] * x2s[n*16 + l2*l2 + b];
            gsh[e] = s * PATH_SC[LO];
          }
        }
      }
    }
    __syncthreads();

    if constexpr (PP < CNT) {      // stage B: T[(c,n)][u] = sum_a g*x1, bf16, swizzled
      constexpr int p  = H_START[LO] + PP;
      constexpr int l1 = H_L1[p];
      constexpr int n1 = 2*l1 + 1;
      const int bn = tid >> 5, u4 = tid & 31;
      const unsigned short* x1r = x1s + ((bn*16 + l1*l1)*128 + u4*4);
      float xf[n1][4];
      #pragma unroll
      for (int a = 0; a < n1; ++a) {
        const uint2 d = *(const uint2*)(x1r + a*128);
        xf[a][0] = bflo(d.x); xf[a][1] = bfhi(d.x);
        xf[a][2] = bflo(d.y); xf[a][3] = bfhi(d.y);
      }
      #pragma unroll
      for (int c = 0; c < NR; ++c) {
        const float* g8 = gsh + (c*16 + bn)*8;
        const float4 ga = *(const float4*)(g8);
        float garr[8];
        garr[0]=ga.x; garr[1]=ga.y; garr[2]=ga.z; garr[3]=ga.w;
        if constexpr (n1 > 4) {
          const float4 gb = *(const float4*)(g8 + 4);
          garr[4]=gb.x; garr[5]=gb.y; garr[6]=gb.z; garr[7]=gb.w;
        }
        float t0=0.f, t1=0.f, t2=0.f, t3=0.f;
        #pragma unroll
        for (int a = 0; a < n1; ++a) {
          t0 += garr[a]*xf[a][0]; t1 += garr[a]*xf[a][1];
          t2 += garr[a]*xf[a][2]; t3 += garr[a]*xf[a][3];
        }
        uint2 o;
        o.x = f2bf(t0) | (f2bf(t1) << 16);
        o.y = f2bf(t2) | (f2bf(t3) << 16);
        const unsigned byte = ((unsigned)(((c*16 + bn)*128 + u4*4)*2)) ^ ((unsigned)((bn & 7) << 4));
        *(uint2*)((char*)Tsh + byte) = o;
      }
    }
    __syncthreads();

    path_iter<LO, PP+1>(tid, x1s, Tsh, gsh, x2s, wT, acc, bfrag);
  }
}

// ---------------------------------------------------------------------------
// Main fused kernel: block = 16 nodes, 512 threads (8 waves x 16-col slices).
// ---------------------------------------------------------------------------
__global__ __launch_bounds__(512, 2)
void so3_main(const float* __restrict__ x1, const float* __restrict__ x2,
              const unsigned short* __restrict__ wT, float* __restrict__ out)
{
  using namespace so3;
  __shared__ unsigned short x1s[16*16*128];   // bf16 x1 tile, 64 KB
  __shared__ unsigned short Tsh[7*16*128];    // bf16 T tile (swizzled), 28 KB
  __shared__ float          gsh[7*16*8];      // g[c][n][a(pad8)], 3.5 KB
  __shared__ float          x2s[256];

  const int tid = threadIdx.x;
  const long n0 = (long)blockIdx.x * MT;

  { // stage x1 (f32 -> bf16) + x2
    const float4* src = (const float4*)(x1 + n0*2048);
    uint2* dst = (uint2*)x1s;
    #pragma unroll
    for (int j = 0; j < 16; ++j) {
      const float4 v = src[tid + j*512];
      uint2 o;
      o.x = f2bf(v.x) | (f2bf(v.y) << 16);
      o.y = f2bf(v.z) | (f2bf(v.w) << 16);
      dst[tid + j*512] = o;
    }
    if (tid < 256) x2s[tid] = x2[n0*16 + tid];
  }
  __syncthreads();

  floatx4 acc[16];
  #pragma unroll
  for (int i = 0; i < 16; ++i) acc[i] = (floatx4){0.f,0.f,0.f,0.f};

  bhalf8 bfrag[2][4];
  path_iter<0,0>(tid, x1s, Tsh, gsh, x2s, wT, acc, bfrag);
  path_iter<1,0>(tid, x1s, Tsh, gsh, x2s, wT, acc, bfrag);
  path_iter<2,0>(tid, x1s, Tsh, gsh, x2s, wT, acc, bfrag);
  path_iter<3,0>(tid, x1s, Tsh, gsh, x2s, wT, acc, bfrag);

  // epilogue: C/D layout col=lane&15, row(node)=(lane>>4)*4+reg  [m89/m91]
  const int lane = tid & 63, wv = tid >> 6, lr = lane & 15, lg = lane >> 4;
  const int v = wv*16 + lr;
  #pragma unroll
  for (int i = 0; i < 16; ++i) {
    #pragma unroll
    for (int r = 0; r < 4; ++r) {
      const int n = lg*4 + r;
      out[((n0 + n)*16 + i)*128 + v] = acc[i][r];
    }
  }
}

// Prep: w (34,128,128) f32 -> wT[p][v][u] bf16 in d_ws (transposed, 1.06 MiB)
__global__ void prep_wT(const float* __restrict__ w, unsigned short* __restrict__ wT)
{
  const int idx = blockIdx.x*256 + threadIdx.x;
  if (idx >= 34*128*128) return;
  const int p = idx >> 14, rem = idx & 16383, u = rem >> 7, v = rem & 127;
  wT[(p << 14) + (v << 7) + u] = (unsigned short)f2bf(w[idx]);
}

extern "C" void kernel_launch(void* const* d_in, const int* in_sizes, int n_in,
                              void* d_out, int out_size, void* d_ws, size_t ws_size,
                              hipStream_t stream)
{
  (void)in_sizes; (void)n_in; (void)out_size; (void)ws_size;
  const float* x1 = (const float*)d_in[0];   // (16384, 16, 128) f32
  const float* x2 = (const float*)d_in[1];   // (16384, 16)      f32
  const float* w  = (const float*)d_in[2];   // (34, 128, 128)   f32
  float* out = (float*)d_out;

  unsigned short* wT = (unsigned short*)d_ws;
  prep_wT<<<dim3(2176), dim3(256), 0, stream>>>(w, wT);
  so3_main<<<dim3(so3::NNODES / so3::MT), dim3(512), 0, stream>>>(x1, x2, wT, out);
}

// Round 3
// 317.358 us; speedup vs baseline: 10.2328x; 1.6325x over previous
//
#include <hip/hip_runtime.h>
#include <cstddef>

// ---------------------------------------------------------------------------
// Compile-time generation of real-basis Clebsch-Gordan tensors (e3nn conv.)
// (verified correct in rounds 1-2)
// ---------------------------------------------------------------------------
namespace so3 {

constexpr int IRR  = 16;
constexpr int CIN  = 128;
constexpr int COUT = 128;
constexpr int NP   = 34;
constexpr int NNODES = 16384;
constexpr int MT   = 16;

constexpr int H_L1[NP] = {0,1,2,3, 0,1,1,1,2,2,2,3,3, 0,1,1,1,2,2,2,2,3,3,3, 0,1,1,2,2,2,3,3,3,3};
constexpr int H_L2[NP] = {0,1,2,3, 1,0,1,2,1,2,3,2,3, 2,1,2,3,0,1,2,3,1,2,3, 3,2,3,1,2,3,0,1,2,3};
constexpr int H_START[4] = {0,4,13,24};
constexpr int H_CNT[4]   = {4,9,11,10};

constexpr double cfac(int n){ double r=1.0; for(int i=2;i<=n;++i) r *= (double)i; return r; }
constexpr double csqrt_(double x){
  if(x <= 0.0) return 0.0;
  double r = x < 1.0 ? 1.0 : x;
  for(int i=0;i<60;++i) r = 0.5*(r + x/r);
  return r;
}
constexpr double m1pow(int k){ return (k & 1) ? -1.0 : 1.0; }

struct CD { double re, im; };
constexpr CD cmul(CD a, CD b){ return CD{a.re*b.re - a.im*b.im, a.re*b.im + a.im*b.re}; }

struct CGDense { double v[7][7][7]; };
constexpr CGDense su2_cg(int j1,int j2,int j3){
  CGDense C{};
  for(int m1=-j1;m1<=j1;++m1){
    for(int m2=-j2;m2<=j2;++m2){
      int m3 = m1+m2;
      if(m3 < -j3 || m3 > j3) continue;
      double pref = csqrt_((2*j3+1) * cfac(j3+j1-j2)*cfac(j3-j1+j2)*cfac(j1+j2-j3)/cfac(j1+j2+j3+1));
      pref *= csqrt_(cfac(j3+m3)*cfac(j3-m3)*cfac(j1-m1)*cfac(j1+m1)*cfac(j2-m2)*cfac(j2+m2));
      double s = 0.0;
      for(int k=0;k<=j1+j2;++k){
        int d0=k, d1=j1+j2-j3-k, d2=j1-m1-k, d3=j2+m2-k, d4=j3-j2+m1+k, d5=j3-j1-m2+k;
        if(d0<0||d1<0||d2<0||d3<0||d4<0||d5<0) continue;
        s += m1pow(k)/(cfac(d0)*cfac(d1)*cfac(d2)*cfac(d3)*cfac(d4)*cfac(d5));
      }
      C.v[m1+j1][m2+j2][m3+j3] = pref*s;
    }
  }
  return C;
}

struct QMat { CD v[7][7]; };
constexpr QMat qmat(int l){
  QMat q{};
  const double r2 = 1.0/csqrt_(2.0);
  for(int m=-l;m<0;++m){
    q.v[l+m][l-m] = CD{r2, 0.0};
    q.v[l+m][l+m] = CD{0.0, -r2};
  }
  q.v[l][l] = CD{1.0, 0.0};
  for(int m=1;m<=l;++m){
    double sgn = m1pow(m);
    q.v[l+m][l+m] = CD{sgn*r2, 0.0};
    q.v[l+m][l-m] = CD{0.0, sgn*r2};
  }
  CD ph = CD{1.0, 0.0};
  int lm = l & 3;
  if(lm==1) ph = CD{0.0,-1.0};
  else if(lm==2) ph = CD{-1.0,0.0};
  else if(lm==3) ph = CD{0.0, 1.0};
  for(int i=0;i<2*l+1;++i)
    for(int j=0;j<2*l+1;++j)
      q.v[i][j] = cmul(q.v[i][j], ph);
  return q;
}

struct RealCG { double v[7][7][7]; };
constexpr RealCG real_cg(int l1,int l2,int l3){
  RealCG W{};
  const CGDense C = su2_cg(l1,l2,l3);
  const QMat q1 = qmat(l1), q2 = qmat(l2), q3 = qmat(l3);
  for(int i=0;i<2*l1+1;++i){
    int alist[2] = {i, 2*l1-i};
    int na = (alist[1]==alist[0]) ? 1 : 2;
    for(int j=0;j<2*l2+1;++j){
      int blist[2] = {j, 2*l2-j};
      int nb = (blist[1]==blist[0]) ? 1 : 2;
      for(int k=0;k<2*l3+1;++k){
        int clist[2] = {k, 2*l3-k};
        int nc = (clist[1]==clist[0]) ? 1 : 2;
        double re = 0.0;
        for(int ai=0;ai<na;++ai) for(int bi=0;bi<nb;++bi) for(int ci=0;ci<nc;++ci){
          int a=alist[ai], b=blist[bi], c=clist[ci];
          double cc = C.v[a][b][c];
          if(cc == 0.0) continue;
          CD t = cmul(cmul(q1.v[a][i], q2.v[b][j]), q3.v[c][k]);
          re += t.re * cc;
        }
        W.v[i][j][k] = re;
      }
    }
  }
  return W;
}

#define DECL_CG(n,a,b,c) constexpr RealCG CGP##n = real_cg(a,b,c);
DECL_CG(0,0,0,0)  DECL_CG(1,1,1,0)  DECL_CG(2,2,2,0)  DECL_CG(3,3,3,0)
DECL_CG(4,0,1,1)  DECL_CG(5,1,0,1)  DECL_CG(6,1,1,1)  DECL_CG(7,1,2,1)
DECL_CG(8,2,1,1)  DECL_CG(9,2,2,1)  DECL_CG(10,2,3,1) DECL_CG(11,3,2,1)
DECL_CG(12,3,3,1) DECL_CG(13,0,2,2) DECL_CG(14,1,1,2) DECL_CG(15,1,2,2)
DECL_CG(16,1,3,2) DECL_CG(17,2,0,2) DECL_CG(18,2,1,2) DECL_CG(19,2,2,2)
DECL_CG(20,2,3,2) DECL_CG(21,3,1,2) DECL_CG(22,3,2,2) DECL_CG(23,3,3,2)
DECL_CG(24,0,3,3) DECL_CG(25,1,2,3) DECL_CG(26,1,3,3) DECL_CG(27,2,1,3)
DECL_CG(28,2,2,3) DECL_CG(29,2,3,3) DECL_CG(30,3,0,3) DECL_CG(31,3,1,3)
DECL_CG(32,3,2,3) DECL_CG(33,3,3,3)
#undef DECL_CG

struct CGTable { float v[NP][7][7][7]; };
constexpr CGTable pack_cg(){
  const RealCG arr[NP] = {CGP0,CGP1,CGP2,CGP3,CGP4,CGP5,CGP6,CGP7,CGP8,CGP9,
                          CGP10,CGP11,CGP12,CGP13,CGP14,CGP15,CGP16,CGP17,CGP18,CGP19,
                          CGP20,CGP21,CGP22,CGP23,CGP24,CGP25,CGP26,CGP27,CGP28,CGP29,
                          CGP30,CGP31,CGP32,CGP33};
  CGTable t{};
  for(int p=0;p<NP;++p)
    for(int i=0;i<7;++i) for(int j=0;j<7;++j) for(int k=0;k<7;++k)
      t.v[p][i][j][k] = (float)arr[p].v[i][j][k];
  return t;
}

constexpr float PATH_SC[4] = {
  (float)(1.0/csqrt_((double)H_CNT[0])), (float)(1.0/csqrt_((double)H_CNT[1])),
  (float)(1.0/csqrt_((double)H_CNT[2])), (float)(1.0/csqrt_((double)H_CNT[3]))
};

} // namespace so3

__constant__ so3::CGTable c_cg = so3::pack_cg();

typedef __attribute__((ext_vector_type(8))) short bhalf8;
typedef __attribute__((ext_vector_type(4))) float floatx4;

__device__ __forceinline__ unsigned f2bf(float f){
  unsigned u = __builtin_bit_cast(unsigned, f);
  return (u + 0x7fffu + ((u>>16)&1u)) >> 16;
}

// ---------------------------------------------------------------------------
// Per-path iterator, ONE barrier per path via double-buffered Tsh/gsh:
//   iter PP: load bfrag(PP-1) | B-global-loads(PP) | A(PP+1) | B-compute(PP)
//            | MFMA(PP-1) | barrier
// Hazards: B(PP)->Tsh[PP&1] vs MFMA(PP-1)<-Tsh[(PP-1)&1]: disjoint buffers.
//          B(PP) overwrites Tsh[(PP-2)&1] read by MFMA(PP-2): separated by
//          the barrier at end of iter PP-1. gsh analogous.
// ---------------------------------------------------------------------------
template<int LO, int PP>
__device__ __forceinline__ void path_iter(const int tid, const long n0,
    const float* __restrict__ x1, unsigned short* __restrict__ Tsh,
    float* __restrict__ gsh, const float* __restrict__ x2s,
    const unsigned short* __restrict__ wT,
    floatx4 (&acc)[16], bhalf8 (&bfrag)[4])
{
  using namespace so3;
  constexpr int NR  = 2*LO + 1;
  constexpr int CNT = H_CNT[LO];
  if constexpr (PP > CNT) { return; }
  else {
    const int lane = tid & 63;
    const int wv   = tid >> 6;
    const int lr   = lane & 15;
    const int lg   = lane >> 4;

    if constexpr (PP > 0) {        // B-frags for path PP-1 (L2-hot; consumed below)
      constexpr int p = H_START[LO] + PP - 1;
      const unsigned short* wp = wT + p*16384 + (wv*16 + lr)*128 + lg*8;
      #pragma unroll
      for (int ks = 0; ks < 4; ++ks)
        bfrag[ks] = *(const bhalf8*)(wp + ks*32);
    }

    // ---- stage B part 1: issue x1 global loads (f32, coalesced float4) ----
    constexpr int n1_cur = (PP < CNT) ? (2*H_L1[H_START[LO] + (PP<CNT?PP:0)] + 1) : 1;
    float4 xf[n1_cur];
    const int bn = tid >> 5, u4 = tid & 31;
    if constexpr (PP < CNT) {
      constexpr int p  = H_START[LO] + PP;
      constexpr int l1 = H_L1[p];
      const float* x1p = x1 + ((size_t)(n0 + bn)*IRR + l1*l1)*CIN + u4*4;
      #pragma unroll
      for (int a = 0; a < n1_cur; ++a)
        xf[a] = *(const float4*)(x1p + a*CIN);
    }

    if constexpr (PP + 1 < CNT) {  // stage A for path PP+1 -> gsh[(PP+1)&1]
      constexpr int p  = H_START[LO] + PP + 1;
      constexpr int l2 = H_L2[p];
      constexpr int n2 = 2*l2 + 1;
      constexpr int GT = NR*16*8;
      float* gout = gsh + ((PP+1)&1)*(7*16*8);
      #pragma unroll
      for (int e0 = 0; e0 < GT; e0 += 512) {
        const int e = e0 + tid;
        if (e < GT) {
          const int a = e & 7, n = (e >> 3) & 15, c = e >> 7;
          if (a < 2*H_L1[p] + 1) {
            float s = 0.f;
            #pragma unroll
            for (int b = 0; b < n2; ++b)
              s += c_cg.v[p][a][b][c] * x2s[n*16 + l2*l2 + b];
            gout[e] = s * PATH_SC[LO];
          }
        }
      }
    }

    if constexpr (PP < CNT) {      // stage B part 2: T = sum_a g*x1 -> Tsh[PP&1]
      const float* gin = gsh + (PP&1)*(7*16*8);
      char* Tbase = (char*)Tsh + (PP&1)*(7*16*128*2);
      #pragma unroll
      for (int c = 0; c < NR; ++c) {
        const float* g8 = gin + (c*16 + bn)*8;
        float garr[8];
        const float4 ga = *(const float4*)(g8);
        garr[0]=ga.x; garr[1]=ga.y; garr[2]=ga.z; garr[3]=ga.w;
        if constexpr (n1_cur > 4) {
          const float4 gb = *(const float4*)(g8 + 4);
          garr[4]=gb.x; garr[5]=gb.y; garr[6]=gb.z; garr[7]=gb.w;
        }
        float t0=0.f, t1=0.f, t2=0.f, t3=0.f;
        #pragma unroll
        for (int a = 0; a < n1_cur; ++a) {
          t0 += garr[a]*xf[a].x; t1 += garr[a]*xf[a].y;
          t2 += garr[a]*xf[a].z; t3 += garr[a]*xf[a].w;
        }
        uint2 o;
        o.x = f2bf(t0) | (f2bf(t1) << 16);
        o.y = f2bf(t2) | (f2bf(t3) << 16);
        const unsigned byte = ((unsigned)(((c*16 + bn)*128 + u4*4)*2)) ^ ((unsigned)((bn & 7) << 4));
        *(uint2*)(Tbase + byte) = o;
      }
    }

    if constexpr (PP > 0) {        // MFMA for path PP-1
      const char* Tbase = (const char*)Tsh + ((PP-1)&1)*(7*16*128*2);
      const unsigned xr = (unsigned)((lr & 7) << 4);
      #pragma unroll
      for (int c = 0; c < NR; ++c) {
        #pragma unroll
        for (int ks = 0; ks < 4; ++ks) {
          const unsigned byte = ((unsigned)((c*16 + lr)*256) + (unsigned)(ks*64 + lg*16)) ^ xr;
          bhalf8 av = *(const bhalf8*)(Tbase + byte);
          acc[LO*LO + c] = __builtin_amdgcn_mfma_f32_16x16x32_bf16(
              av, bfrag[ks], acc[LO*LO + c], 0, 0, 0);
        }
      }
    }
    __syncthreads();

    path_iter<LO, PP+1>(tid, n0, x1, Tsh, gsh, x2s, wT, acc, bfrag);
  }
}

// Prologue per lo-group: stage A for path 0 -> gsh[0]
template<int LO>
__device__ __forceinline__ void stage_a0(const int tid, float* __restrict__ gsh,
                                         const float* __restrict__ x2s)
{
  using namespace so3;
  constexpr int NR = 2*LO + 1;
  constexpr int p  = H_START[LO];
  constexpr int l1 = H_L1[p], l2 = H_L2[p];
  constexpr int n2 = 2*l2 + 1;
  constexpr int GT = NR*16*8;
  #pragma unroll
  for (int e0 = 0; e0 < GT; e0 += 512) {
    const int e = e0 + tid;
    if (e < GT) {
      const int a = e & 7, n = (e >> 3) & 15, c = e >> 7;
      if (a < 2*l1 + 1) {
        float s = 0.f;
        #pragma unroll
        for (int b = 0; b < n2; ++b)
          s += c_cg.v[p][a][b][c] * x2s[n*16 + l2*l2 + b];
        gsh[e] = s * PATH_SC[LO];
      }
    }
  }
}

// ---------------------------------------------------------------------------
// Main kernel: block = 16 nodes, 512 threads, 2 blocks/CU (LDS 64.5 KB).
// ---------------------------------------------------------------------------
__global__ __launch_bounds__(512, 4)
void so3_main(const float* __restrict__ x1, const float* __restrict__ x2,
              const unsigned short* __restrict__ wT, float* __restrict__ out)
{
  using namespace so3;
  __shared__ unsigned short Tsh[2*7*16*128];   // 56 KB, double-buffered, swizzled
  __shared__ float          gsh[2*7*16*8];     // 7 KB, double-buffered
  __shared__ float          x2s[256];

  const int tid = threadIdx.x;
  const long n0 = (long)blockIdx.x * MT;

  if (tid < 256) x2s[tid] = x2[n0*16 + tid];
  __syncthreads();

  floatx4 acc[16];
  #pragma unroll
  for (int i = 0; i < 16; ++i) acc[i] = (floatx4){0.f,0.f,0.f,0.f};

  bhalf8 bfrag[4];

  stage_a0<0>(tid, gsh, x2s); __syncthreads();
  path_iter<0,0>(tid, n0, x1, Tsh, gsh, x2s, wT, acc, bfrag);
  stage_a0<1>(tid, gsh, x2s); __syncthreads();
  path_iter<1,0>(tid, n0, x1, Tsh, gsh, x2s, wT, acc, bfrag);
  stage_a0<2>(tid, gsh, x2s); __syncthreads();
  path_iter<2,0>(tid, n0, x1, Tsh, gsh, x2s, wT, acc, bfrag);
  stage_a0<3>(tid, gsh, x2s); __syncthreads();
  path_iter<3,0>(tid, n0, x1, Tsh, gsh, x2s, wT, acc, bfrag);

  // epilogue: C/D layout col=lane&15, row(node)=(lane>>4)*4+reg
  const int lane = tid & 63, wv = tid >> 6, lr = lane & 15, lg = lane >> 4;
  const int v = wv*16 + lr;
  #pragma unroll
  for (int i = 0; i < 16; ++i) {
    #pragma unroll
    for (int r = 0; r < 4; ++r) {
      const long n = n0 + lg*4 + r;
      out[(n*16 + i)*128 + v] = acc[i][r];
    }
  }
}

// Prep: w (34,128,128) f32 -> wT[p][v][u] bf16 in d_ws (transposed, 1.06 MiB)
__global__ void prep_wT(const float* __restrict__ w, unsigned short* __restrict__ wT)
{
  const int idx = blockIdx.x*256 + threadIdx.x;
  if (idx >= 34*128*128) return;
  const int p = idx >> 14, rem = idx & 16383, u = rem >> 7, v = rem & 127;
  wT[(p << 14) + (v << 7) + u] = (unsigned short)f2bf(w[idx]);
}

extern "C" void kernel_launch(void* const* d_in, const int* in_sizes, int n_in,
                              void* d_out, int out_size, void* d_ws, size_t ws_size,
                              hipStream_t stream)
{
  (void)in_sizes; (void)n_in; (void)out_size; (void)ws_size;
  const float* x1 = (const float*)d_in[0];
  const float* x2 = (const float*)d_in[1];
  const float* w  = (const float*)d_in[2];
  float* out = (float*)d_out;

  unsigned short* wT = (unsigned short*)d_ws;
  prep_wT<<<dim3(2176), dim3(256), 0, stream>>>(w, wT);
  so3_main<<<dim3(so3::NNODES / so3::MT), dim3(512), 0, stream>>>(x1, x2, wT, out);
}